// Round 19
// baseline (177.105 us; speedup 1.0000x reference)
//
#include <hip/hip_runtime.h>
#include <math.h>

#define NT 16384
#define DM 2048
#define NE 64
#define TOPK 8
#define LTAX 0.04f
#define HYST 0.1f
#define ALPHA 0.7f

typedef unsigned int u32;
typedef unsigned short u16;
typedef unsigned long long u64;
typedef __attribute__((ext_vector_type(8))) short bf16x8;
typedef __attribute__((ext_vector_type(4))) float f32x4;

__device__ __forceinline__ float warp4_sum(float v) {
  v += __shfl_xor(v, 1); v += __shfl_xor(v, 2); return v;
}
__device__ __forceinline__ float warp4_max(float v) {
  v = fmaxf(v, __shfl_xor(v, 1)); v = fmaxf(v, __shfl_xor(v, 2)); return v;
}
__device__ __forceinline__ u16 f2bf(float f) {   // RNE f32->bf16
  u32 u = __float_as_uint(f);
  return (u16)((u + 0x7fffu + ((u >> 16) & 1u)) >> 16);
}
__device__ __forceinline__ float bf2f(u16 h) { return __uint_as_float(((u32)h) << 16); }

__device__ __forceinline__ void split3(float a, short& h, short& m, short& l) {
  u16 hh = f2bf(a);  float r1 = a - bf2f(hh);     // exact (Sterbenz)
  u16 mm = f2bf(r1); float r2 = r1 - bf2f(mm);    // exact
  h = (short)hh; m = (short)mm; l = (short)f2bf(r2);
}

// fixed-point 2^32: exact-commutative integer atomics => deterministic
__device__ __forceinline__ u64 to_fx(float v) {
  return (u64)__double2ll_rn((double)v * 4294967296.0);
}

// ---------------- K0: fused W-split (row-major hi/mid/lo) + zero ------------
__global__ void k_init(const float* __restrict__ W, u16* __restrict__ Wh,
                       u16* __restrict__ Wm, u16* __restrict__ Wl,
                       u64* __restrict__ zp) {
  const int bid = blockIdx.x, tid = threadIdx.x;
  if (bid < 128) {
    int idx = (bid * 256 + tid) * 4;
    float4 v = *(const float4*)(W + idx);
    short h[4], m[4], l[4];
    split3(v.x, h[0], m[0], l[0]);
    split3(v.y, h[1], m[1], l[1]);
    split3(v.z, h[2], m[2], l[2]);
    split3(v.w, h[3], m[3], l[3]);
    *(ushort4*)(Wh + idx) = make_ushort4((u16)h[0], (u16)h[1], (u16)h[2], (u16)h[3]);
    *(ushort4*)(Wm + idx) = make_ushort4((u16)m[0], (u16)m[1], (u16)m[2], (u16)m[3]);
    *(ushort4*)(Wl + idx) = make_ushort4((u16)l[0], (u16)l[1], (u16)l[2], (u16)l[3]);
  } else {
    int i = (bid - 128) * 256 + tid;
    if (i < 26624) zp[i] = 0ull;
  }
}

// ---------------- K1: LDS MFMA GEMM, split-K=8, prefetch-pipelined ----------
// Same as R18 (single-buffer, 5 blocks/CU) but chunk t+1's global loads are
// issued AFTER the write barrier and BEFORE chunk t's compute, so HBM/L2
// latency hides under MFMA+ds_read instead of stalling the WRITE phase.
// MFMA op order identical to R18 -> bit-identical results.
__launch_bounds__(256, 5)
__global__ void k_gemm(const float* __restrict__ x, const u16* __restrict__ Whg,
                       const u16* __restrict__ Wmg, const u16* __restrict__ Wlg,
                       float* __restrict__ Lpart) {
  __shared__ __align__(16) u16 XS[15360];   // 6 arrays x [64][40] u16
  const int tid = threadIdx.x;
  const int bid = blockIdx.x;
  const int tile = bid >> 3, ks = bid & 7;
  const int row0 = tile * 64;
  const int k0 = ks * 256;
  const int lane = tid & 63, w = tid >> 6, l15 = lane & 15, l4 = lane >> 4;
  const int srow = tid >> 2, c8 = (tid & 3) * 8;
  const int stoff = srow * 40 + c8;

  f32x4 accA[4], accB[4];
#pragma unroll
  for (int eb = 0; eb < 4; eb++) { accA[eb] = (f32x4)0.f; accB[eb] = (f32x4)0.f; }

  float4 xq0, xq1;
  uint4 whv, wmv, wlv;
  const float* xrowp = x + (size_t)(row0 + srow) * DM + k0 + c8;
  const u16* whp = Whg + srow * DM + k0 + c8;
  const u16* wmp = Wmg + srow * DM + k0 + c8;
  const u16* wlp = Wlg + srow * DM + k0 + c8;

#define LOADCH(KC) { \
    xq0 = *(const float4*)(xrowp + (KC)); \
    xq1 = *(const float4*)(xrowp + (KC) + 4); \
    whv = *(const uint4*)(whp + (KC)); \
    wmv = *(const uint4*)(wmp + (KC)); \
    wlv = *(const uint4*)(wlp + (KC)); }

#define WRITECH() { \
    short ha[8], ma[8], la[8]; \
    split3(xq0.x, ha[0], ma[0], la[0]); \
    split3(xq0.y, ha[1], ma[1], la[1]); \
    split3(xq0.z, ha[2], ma[2], la[2]); \
    split3(xq0.w, ha[3], ma[3], la[3]); \
    split3(xq1.x, ha[4], ma[4], la[4]); \
    split3(xq1.y, ha[5], ma[5], la[5]); \
    split3(xq1.z, ha[6], ma[6], la[6]); \
    split3(xq1.w, ha[7], ma[7], la[7]); \
    bf16x8 xh8, xm8, xl8; \
    _Pragma("unroll") \
    for (int z = 0; z < 8; z++) { xh8[z] = ha[z]; xm8[z] = ma[z]; xl8[z] = la[z]; } \
    *(bf16x8*)(XS + 0     + stoff) = xh8; \
    *(bf16x8*)(XS + 2560  + stoff) = xm8; \
    *(bf16x8*)(XS + 5120  + stoff) = xl8; \
    *(uint4*)(XS + 7680  + stoff) = whv; \
    *(uint4*)(XS + 10240 + stoff) = wmv; \
    *(uint4*)(XS + 12800 + stoff) = wlv; }

#define COMPUTECH() { \
    const int ar = (w * 16 + l15) * 40 + l4 * 8; \
    bf16x8 ah = *(const bf16x8*)(XS + 0    + ar); \
    bf16x8 am = *(const bf16x8*)(XS + 2560 + ar); \
    bf16x8 al = *(const bf16x8*)(XS + 5120 + ar); \
    _Pragma("unroll") \
    for (int eb = 0; eb < 4; eb++) { \
      const int br = (eb * 16 + l15) * 40 + l4 * 8; \
      bf16x8 bh = *(const bf16x8*)(XS + 7680  + br); \
      bf16x8 bm = *(const bf16x8*)(XS + 10240 + br); \
      bf16x8 bl = *(const bf16x8*)(XS + 12800 + br); \
      accA[eb] = __builtin_amdgcn_mfma_f32_16x16x32_bf16(ah, bh, accA[eb], 0, 0, 0); \
      accB[eb] = __builtin_amdgcn_mfma_f32_16x16x32_bf16(ah, bm, accB[eb], 0, 0, 0); \
      accB[eb] = __builtin_amdgcn_mfma_f32_16x16x32_bf16(am, bh, accB[eb], 0, 0, 0); \
      accB[eb] = __builtin_amdgcn_mfma_f32_16x16x32_bf16(am, bm, accB[eb], 0, 0, 0); \
      accB[eb] = __builtin_amdgcn_mfma_f32_16x16x32_bf16(ah, bl, accB[eb], 0, 0, 0); \
      accB[eb] = __builtin_amdgcn_mfma_f32_16x16x32_bf16(al, bh, accB[eb], 0, 0, 0); \
    } }

  LOADCH(0);
#pragma unroll 1
  for (int t = 0; t < 8; t++) {
    __syncthreads();          // previous chunk's compute done before overwrite
    WRITECH();                // stage regs of chunk t (stalls only on vmcnt(t))
    __syncthreads();
    if (t < 7) LOADCH((t + 1) * 32);   // issue next-chunk loads...
    COMPUTECH();                        // ...hidden under this chunk's compute
  }

  // single f64 flush (same accumulation order as R18's passed path)
  // C/D layout: col=lane&15 (expert), row=(lane>>4)*4+reg (token) [verified]
  float* outp = Lpart + (size_t)ks * NT * NE;
#pragma unroll
  for (int eb = 0; eb < 4; eb++)
#pragma unroll
    for (int r = 0; r < 4; r++) {
      int trow = w * 16 + l4 * 4 + r;
      outp[(size_t)(row0 + trow) * NE + eb * 16 + l15] =
          (float)((double)accA[eb][r] + (double)accB[eb][r]);
    }
}

// ---------------- K2: reduce 8 partials + center + softmax1 + gram ----------
__launch_bounds__(256)
__global__ void k_post(const float* __restrict__ Lpart, const float* __restrict__ b,
                       float* __restrict__ Lbuf, u64* __restrict__ CmAcc) {
  __shared__ float ms[64 * 68];
  const int tid = threadIdx.x, bid = blockIdx.x;
  const int tg = tid >> 2, q = tid & 3;
  const int row = bid * 64 + tg;
  float l[16], m[16];
  {
    double acc[16];
#pragma unroll
    for (int j = 0; j < 16; j++) acc[j] = 0.0;
#pragma unroll 1
    for (int ks = 0; ks < 8; ks++) {
      const float* p = Lpart + (size_t)ks * NT * NE + (size_t)row * NE + q * 16;
#pragma unroll
      for (int i = 0; i < 4; i++) {
        float4 v = *(const float4*)(p + i * 4);
        acc[i * 4 + 0] += (double)v.x; acc[i * 4 + 1] += (double)v.y;
        acc[i * 4 + 2] += (double)v.z; acc[i * 4 + 3] += (double)v.w;
      }
    }
#pragma unroll
    for (int i = 0; i < 4; i++) {
      float4 bv = *(const float4*)(b + q * 16 + i * 4);
      l[i * 4 + 0] = (float)acc[i * 4 + 0] + bv.x;
      l[i * 4 + 1] = (float)acc[i * 4 + 1] + bv.y;
      l[i * 4 + 2] = (float)acc[i * 4 + 2] + bv.z;
      l[i * 4 + 3] = (float)acc[i * 4 + 3] + bv.w;
    }
    float s = 0.f;
#pragma unroll
    for (int j = 0; j < 16; j++) s += l[j];
    s = warp4_sum(s);
    const float mean = s * (1.0f / 64.0f);
    float mx = -1e30f;
#pragma unroll
    for (int j = 0; j < 16; j++) { l[j] -= mean; mx = fmaxf(mx, l[j]); }
    mx = warp4_max(mx);
#pragma unroll
    for (int i = 0; i < 4; i++)
      *(float4*)(Lbuf + (size_t)row * NE + q * 16 + i * 4) =
          make_float4(l[i * 4], l[i * 4 + 1], l[i * 4 + 2], l[i * 4 + 3]);
    float ps = 0.f;
#pragma unroll
    for (int j = 0; j < 16; j++) { m[j] = expf(l[j] - mx); ps += m[j]; }
    ps = warp4_sum(ps);
    const float inv = 1.0f / ps;
#pragma unroll
    for (int j = 0; j < 16; j++) m[j] *= inv;
#pragma unroll
    for (int i = 0; i < 4; i++)
      *(float4*)(ms + tg * 68 + q * 16 + i * 4) =
          make_float4(m[i * 4], m[i * 4 + 1], m[i * 4 + 2], m[i * 4 + 3]);
  }
  __syncthreads();
  // gram partial -> slotted fx atomics (slot = bid & 3)
  const int gi0 = (tid >> 4) * 4;
  const int gj0 = (tid & 15) * 4;
  float ga[4][4];
#pragma unroll
  for (int a = 0; a < 4; a++)
#pragma unroll
    for (int c = 0; c < 4; c++) ga[a][c] = 0.f;
  for (int t = 0; t < 64; t++) {
    float4 a = *(const float4*)(ms + t * 68 + gi0);
    float4 bb = *(const float4*)(ms + t * 68 + gj0);
    ga[0][0] = fmaf(a.x, bb.x, ga[0][0]); ga[0][1] = fmaf(a.x, bb.y, ga[0][1]);
    ga[0][2] = fmaf(a.x, bb.z, ga[0][2]); ga[0][3] = fmaf(a.x, bb.w, ga[0][3]);
    ga[1][0] = fmaf(a.y, bb.x, ga[1][0]); ga[1][1] = fmaf(a.y, bb.y, ga[1][1]);
    ga[1][2] = fmaf(a.y, bb.z, ga[1][2]); ga[1][3] = fmaf(a.y, bb.w, ga[1][3]);
    ga[2][0] = fmaf(a.z, bb.x, ga[2][0]); ga[2][1] = fmaf(a.z, bb.y, ga[2][1]);
    ga[2][2] = fmaf(a.z, bb.z, ga[2][2]); ga[2][3] = fmaf(a.z, bb.w, ga[2][3]);
    ga[3][0] = fmaf(a.w, bb.x, ga[3][0]); ga[3][1] = fmaf(a.w, bb.y, ga[3][1]);
    ga[3][2] = fmaf(a.w, bb.z, ga[3][2]); ga[3][3] = fmaf(a.w, bb.w, ga[3][3]);
  }
  u64* slot = CmAcc + (size_t)(bid & 3) * 4096;
#pragma unroll
  for (int ii = 0; ii < 4; ii++)
#pragma unroll
    for (int jj = 0; jj < 4; jj++)
      atomicAdd(slot + (gi0 + ii) * 64 + gj0 + jj, to_fx(ga[ii][jj]));
}

// ---------------- K3: correction + softmax2 -> M0; emit P0 ------------------
__launch_bounds__(256)
__global__ void k_correct(const float* __restrict__ Lbuf, const u64* __restrict__ CmAcc,
                          float* __restrict__ M0, u64* __restrict__ p0Acc) {
  __shared__ float ms[64 * 68];
  __shared__ float Cs[4096];
  __shared__ float cred[256];
  const int tid = threadIdx.x, bid = blockIdx.x;
  const int tg = tid >> 2, q = tid & 3;
  const int lane = tid & 63, w = tid >> 6;
  const int row = bid * 64 + tg;
  float l[16], m[16];
#pragma unroll
  for (int i = 0; i < 4; i++) {
    float4 lv = *(const float4*)(Lbuf + (size_t)row * NE + q * 16 + i * 4);
    l[i * 4 + 0] = lv.x; l[i * 4 + 1] = lv.y; l[i * 4 + 2] = lv.z; l[i * 4 + 3] = lv.w;
  }
  {
    float mx = -1e30f;
#pragma unroll
    for (int j = 0; j < 16; j++) mx = fmaxf(mx, l[j]);
    mx = warp4_max(mx);
    float ps = 0.f;
#pragma unroll
    for (int j = 0; j < 16; j++) { m[j] = expf(l[j] - mx); ps += m[j]; }
    ps = warp4_sum(ps);
    const float inv = 1.0f / ps;
#pragma unroll
    for (int j = 0; j < 16; j++) m[j] *= inv;
#pragma unroll
    for (int i = 0; i < 4; i++)
      *(float4*)(ms + tg * 68 + q * 16 + i * 4) =
          make_float4(m[i * 4], m[i * 4 + 1], m[i * 4 + 2], m[i * 4 + 3]);
  }
#pragma unroll 4
  for (int i = 0; i < 16; i++) {
    int idx = tid + i * 256;
    u64 s = CmAcc[idx] + CmAcc[4096 + idx] + CmAcc[8192 + idx] + CmAcc[12288 + idx];
    float v = (float)((double)s * (1.0 / 4294967296.0));
    int r = idx >> 6, c = idx & 63;
    Cs[idx] = (r == c) ? 0.f : v;
  }
  __syncthreads();
  {
    float g[16];
#pragma unroll
    for (int j = 0; j < 16; j++) g[j] = 0.f;
    for (int f = 0; f < 64; f++) {
      float mf = ms[tg * 68 + f];
#pragma unroll
      for (int i = 0; i < 4; i++) {
        float4 cv = *(const float4*)(Cs + f * 64 + q * 16 + i * 4);
        g[i * 4 + 0] = fmaf(mf, cv.x, g[i * 4 + 0]);
        g[i * 4 + 1] = fmaf(mf, cv.y, g[i * 4 + 1]);
        g[i * 4 + 2] = fmaf(mf, cv.z, g[i * 4 + 2]);
        g[i * 4 + 3] = fmaf(mf, cv.w, g[i * 4 + 3]);
      }
    }
    float dot = 0.f;
#pragma unroll
    for (int j = 0; j < 16; j++) { g[j] *= 4.f; dot += m[j] * g[j]; }
    dot = warp4_sum(dot);
    float mx = -1e30f;
#pragma unroll
    for (int j = 0; j < 16; j++) {
      l[j] = l[j] - LTAX * (m[j] * (g[j] - dot));
      mx = fmaxf(mx, l[j]);
    }
    mx = warp4_max(mx);
    float ps = 0.f;
#pragma unroll
    for (int j = 0; j < 16; j++) { m[j] = expf(l[j] - mx); ps += m[j]; }
    ps = warp4_sum(ps);
    const float inv = 1.0f / ps;
#pragma unroll
    for (int j = 0; j < 16; j++) m[j] *= inv;
#pragma unroll
    for (int i = 0; i < 4; i++)
      *(float4*)(M0 + (size_t)row * NE + q * 16 + i * 4) =
          make_float4(m[i * 4], m[i * 4 + 1], m[i * 4 + 2], m[i * 4 + 3]);
  }
  {
    float cs[16];
#pragma unroll
    for (int j = 0; j < 16; j++) cs[j] = m[j];
#pragma unroll
    for (int j = 0; j < 16; j++) {
      cs[j] += __shfl_xor(cs[j], 4);  cs[j] += __shfl_xor(cs[j], 8);
      cs[j] += __shfl_xor(cs[j], 16); cs[j] += __shfl_xor(cs[j], 32);
    }
    if ((lane >> 2) == 0) {
#pragma unroll
      for (int j = 0; j < 16; j++) cred[w * 64 + lane * 16 + j] = cs[j];
    }
    __syncthreads();
    if (tid < 64)
      atomicAdd(p0Acc + (size_t)(bid & 15) * 64 + tid,
                to_fx(cred[tid] + cred[64 + tid] + cred[128 + tid] + cred[192 + tid]));
  }
}

// ---------------- K4: one factored Sinkhorn iteration -----------------------
__launch_bounds__(256)
__global__ void k_sink(const float* __restrict__ M0, const u64* __restrict__ pin,
                       u64* __restrict__ pout) {
  __shared__ u64 pred[4][64];
  __shared__ float fac[64];
  __shared__ float cred[256];
  const int tid = threadIdx.x, bid = blockIdx.x;
  const int tg = tid >> 2, q = tid & 3;
  const int lane = tid & 63, w = tid >> 6;
  const int row = bid * 64 + tg;
  {
    const int grp = tid >> 6, e = tid & 63;
    pred[grp][e] = pin[grp * 64 + e] + pin[(grp + 4) * 64 + e] +
                   pin[(grp + 8) * 64 + e] + pin[(grp + 12) * 64 + e];
  }
  __syncthreads();
  if (tid < 64) {
    u64 s = pred[0][tid] + pred[1][tid] + pred[2][tid] + pred[3][tid];
    float P = (float)((double)s * (1.0 / 4294967296.0));
    fac[tid] = 256.0f / fmaxf(P, 1e-30f);     // V(e)
  }
  __syncthreads();
  float mv[16];
#pragma unroll
  for (int i = 0; i < 4; i++) {
    float4 v = *(const float4*)(M0 + (size_t)row * NE + q * 16 + i * 4);
    mv[i * 4 + 0] = v.x; mv[i * 4 + 1] = v.y; mv[i * 4 + 2] = v.z; mv[i * 4 + 3] = v.w;
  }
  float Q = 0.f;
#pragma unroll
  for (int j = 0; j < 16; j++) Q = fmaf(mv[j], fac[q * 16 + j], Q);
  Q = warp4_sum(Q);
  const float U = 1.0f / fmaxf(Q, 1e-30f);
  float cs[16];
#pragma unroll
  for (int j = 0; j < 16; j++) cs[j] = U * mv[j];
#pragma unroll
  for (int j = 0; j < 16; j++) {
    cs[j] += __shfl_xor(cs[j], 4);  cs[j] += __shfl_xor(cs[j], 8);
    cs[j] += __shfl_xor(cs[j], 16); cs[j] += __shfl_xor(cs[j], 32);
  }
  if ((lane >> 2) == 0) {
#pragma unroll
    for (int j = 0; j < 16; j++) cred[w * 64 + lane * 16 + j] = cs[j];
  }
  __syncthreads();
  if (tid < 64)
    atomicAdd(pout + (size_t)(bid & 15) * 64 + tid,
              to_fx(cred[tid] + cred[64 + tid] + cred[128 + tid] + cred[192 + tid]));
}

// ---------------- K5: final M10 + damping + hysteresis + topk ---------------
__launch_bounds__(256)
__global__ void k_final(const float* __restrict__ M0, const u64* __restrict__ pin,
                        const float* __restrict__ pp, const void* __restrict__ pmask,
                        float* __restrict__ out) {
  __shared__ u64 pred[4][64];
  __shared__ float fac[64];
  __shared__ int s_cnt[256];
  __shared__ int s_flag;
  const int tid = threadIdx.x, bid = blockIdx.x;
  const int tg = tid >> 2, q = tid & 3;
  const int lane = tid & 63;
  const int row = bid * 64 + tg;

  {
    uint4 v = ((const uint4*)pmask)[tid];
    int c = 0; u32 ww;
    ww = v.x; c += ((ww & 0xffu) != 0) + ((ww & 0xff00u) != 0) + ((ww & 0xff0000u) != 0) + ((ww & 0xff000000u) != 0);
    ww = v.y; c += ((ww & 0xffu) != 0) + ((ww & 0xff00u) != 0) + ((ww & 0xff0000u) != 0) + ((ww & 0xff000000u) != 0);
    ww = v.z; c += ((ww & 0xffu) != 0) + ((ww & 0xff00u) != 0) + ((ww & 0xff0000u) != 0) + ((ww & 0xff000000u) != 0);
    ww = v.w; c += ((ww & 0xffu) != 0) + ((ww & 0xff00u) != 0) + ((ww & 0xff0000u) != 0) + ((ww & 0xff000000u) != 0);
    s_cnt[tid] = c;
    __syncthreads();
    for (int s = 128; s; s >>= 1) { if (tid < s) s_cnt[tid] += s_cnt[tid + s]; __syncthreads(); }
    if (tid == 0) { int n = s_cnt[0]; s_flag = (n > 384) ? 0 : ((n > 192) ? 2 : 1); }
  }
  {
    const int grp = tid >> 6, e = tid & 63;
    pred[grp][e] = pin[grp * 64 + e] + pin[(grp + 4) * 64 + e] +
                   pin[(grp + 8) * 64 + e] + pin[(grp + 12) * 64 + e];
  }
  __syncthreads();
  if (tid < 64) {
    u64 s = pred[0][tid] + pred[1][tid] + pred[2][tid] + pred[3][tid];
    float P = (float)((double)s * (1.0 / 4294967296.0));
    fac[tid] = 256.0f / fmaxf(P, 1e-30f);     // V10
  }
  __syncthreads();

  float mv[16];
#pragma unroll
  for (int i = 0; i < 4; i++) {
    float4 v = *(const float4*)(M0 + (size_t)row * NE + q * 16 + i * 4);
    mv[i * 4 + 0] = v.x; mv[i * 4 + 1] = v.y; mv[i * 4 + 2] = v.z; mv[i * 4 + 3] = v.w;
  }
  float Q = 0.f;
#pragma unroll
  for (int j = 0; j < 16; j++) Q = fmaf(mv[j], fac[q * 16 + j], Q);
  Q = warp4_sum(Q);
  const float U = 1.0f / fmaxf(Q, 1e-30f);
  float m[16];
#pragma unroll
  for (int j = 0; j < 16; j++) m[j] = U * mv[j] * fac[q * 16 + j];   // M10 row

  const int flag = s_flag;
  float pv[16], mk[16];
#pragma unroll
  for (int i = 0; i < 4; i++) {
    float4 v = *(const float4*)(pp + (size_t)row * NE + q * 16 + i * 4);
    pv[i * 4 + 0] = v.x; pv[i * 4 + 1] = v.y; pv[i * 4 + 2] = v.z; pv[i * 4 + 3] = v.w;
  }
  if (flag == 0) {
    const u32* pb = (const u32*)pmask + row * 16 + q * 4;
#pragma unroll
    for (int i = 0; i < 4; i++) {
      u32 ww = pb[i];
      mk[i * 4 + 0] = (ww & 0xffu) ? 1.f : 0.f;
      mk[i * 4 + 1] = (ww & 0xff00u) ? 1.f : 0.f;
      mk[i * 4 + 2] = (ww & 0xff0000u) ? 1.f : 0.f;
      mk[i * 4 + 3] = (ww & 0xff000000u) ? 1.f : 0.f;
    }
  } else if (flag == 1) {
    const int* pb = (const int*)pmask + (size_t)row * NE + q * 16;
#pragma unroll
    for (int j = 0; j < 16; j++) mk[j] = pb[j] ? 1.f : 0.f;
  } else {
    const float* pb = (const float*)pmask + (size_t)row * NE + q * 16;
#pragma unroll
    for (int j = 0; j < 16; j++) mk[j] = (pb[j] != 0.f) ? 1.f : 0.f;
  }
  float msum = 0.f;
#pragma unroll
  for (int j = 0; j < 16; j++) msum += mk[j];
  msum = warp4_sum(msum);
  const float hscale = HYST / fmaxf(msum, 1.0f);
  float v[16];
  float s = 0.f;
#pragma unroll
  for (int j = 0; j < 16; j++) {
    float base = (1.f - ALPHA) * pv[j] + ALPHA * m[j];
    v[j] = (1.f - HYST) * base + hscale * mk[j];
    s += v[j];
  }
  s = warp4_sum(s);
  const float inv = 1.0f / fmaxf(s, 1e-12f);
#pragma unroll
  for (int j = 0; j < 16; j++) v[j] *= inv;

  float* mout = out;
  float* kout = out + (size_t)NT * NE;
#pragma unroll
  for (int i = 0; i < 4; i++)
    *(float4*)(mout + (size_t)row * NE + q * 16 + i * 4) =
        make_float4(v[i * 4], v[i * 4 + 1], v[i * 4 + 2], v[i * 4 + 3]);

  int cnt[16];
#pragma unroll
  for (int j = 0; j < 16; j++) cnt[j] = 0;
  const int base = lane & ~3;
#pragma unroll
  for (int oq = 0; oq < 4; oq++) {
#pragma unroll
    for (int j2 = 0; j2 < 16; j2++) {
      float ov = __shfl(v[j2], base + oq, 64);
      int oe = oq * 16 + j2;
#pragma unroll
      for (int j = 0; j < 16; j++) {
        int me = q * 16 + j;
        if (ov > v[j] || (ov == v[j] && oe < me)) cnt[j]++;
      }
    }
  }
#pragma unroll
  for (int i = 0; i < 4; i++)
    *(float4*)(kout + (size_t)row * NE + q * 16 + i * 4) =
        make_float4(cnt[i * 4] < TOPK ? 1.f : 0.f, cnt[i * 4 + 1] < TOPK ? 1.f : 0.f,
                    cnt[i * 4 + 2] < TOPK ? 1.f : 0.f, cnt[i * 4 + 3] < TOPK ? 1.f : 0.f);
}

extern "C" void kernel_launch(void* const* d_in, const int* in_sizes, int n_in,
                              void* d_out, int out_size, void* d_ws, size_t ws_size,
                              hipStream_t stream) {
  const float* x = (const float*)d_in[0];
  const float* W = (const float*)d_in[1];
  const float* b = (const float*)d_in[2];
  const float* pp = (const float*)d_in[3];
  const void* pmask = d_in[4];
  float* out = (float*)d_out;

  unsigned char* wsb = (unsigned char*)d_ws;
  u16* Wh = (u16*)(wsb);                          // 256 KB
  u16* Wm = (u16*)(wsb + 262144);                 // 256 KB
  u16* Wl = (u16*)(wsb + 524288);                 // 256 KB
  float* Lpart = (float*)(wsb + 786432);          // 8 slices * 4 MB = 32 MB
  float* Lbuf = (float*)(wsb + 34340864);         // 4 MB
  float* M0buf = (float*)(wsb + 38535168);        // 4 MB
  u64* CmAcc = (u64*)(wsb + 42729472);            // 128 KB
  u64* pAcc = (u64*)(wsb + 42860544);             // 80 KB

  k_init<<<232, 256, 0, stream>>>(W, Wh, Wm, Wl, CmAcc);   // split W + zero acc
  k_gemm<<<2048, 256, 0, stream>>>(x, Wh, Wm, Wl, Lpart);
  k_post<<<256, 256, 0, stream>>>(Lpart, b, Lbuf, CmAcc);
  k_correct<<<256, 256, 0, stream>>>(Lbuf, CmAcc, M0buf, pAcc);
  for (int k = 1; k <= 9; k++)
    k_sink<<<256, 256, 0, stream>>>(M0buf, pAcc + (size_t)(k - 1) * 1024,
                                    pAcc + (size_t)k * 1024);
  k_final<<<256, 256, 0, stream>>>(M0buf, pAcc + (size_t)9 * 1024, pp, pmask, out);
}

// Round 20
// 176.025 us; speedup vs baseline: 1.0061x; 1.0061x over previous
//
#include <hip/hip_runtime.h>
#include <math.h>

#define NT 16384
#define DM 2048
#define NE 64
#define TOPK 8
#define LTAX 0.04f
#define HYST 0.1f
#define ALPHA 0.7f

typedef unsigned int u32;
typedef unsigned short u16;
typedef unsigned long long u64;
typedef __attribute__((ext_vector_type(8))) short bf16x8;
typedef __attribute__((ext_vector_type(4))) float f32x4;

__device__ __forceinline__ float warp4_sum(float v) {
  v += __shfl_xor(v, 1); v += __shfl_xor(v, 2); return v;
}
__device__ __forceinline__ float warp4_max(float v) {
  v = fmaxf(v, __shfl_xor(v, 1)); v = fmaxf(v, __shfl_xor(v, 2)); return v;
}
__device__ __forceinline__ u16 f2bf(float f) {   // RNE f32->bf16
  u32 u = __float_as_uint(f);
  return (u16)((u + 0x7fffu + ((u >> 16) & 1u)) >> 16);
}
__device__ __forceinline__ float bf2f(u16 h) { return __uint_as_float(((u32)h) << 16); }

__device__ __forceinline__ void split3(float a, short& h, short& m, short& l) {
  u16 hh = f2bf(a);  float r1 = a - bf2f(hh);     // exact (Sterbenz)
  u16 mm = f2bf(r1); float r2 = r1 - bf2f(mm);    // exact
  h = (short)hh; m = (short)mm; l = (short)f2bf(r2);
}

// fixed-point 2^32: exact-commutative integer atomics => deterministic
__device__ __forceinline__ u64 to_fx(float v) {
  return (u64)__double2ll_rn((double)v * 4294967296.0);
}

// ---------------- K0: fused W-split (row-major hi/mid/lo) + zero ------------
__global__ void k_init(const float* __restrict__ W, u16* __restrict__ Wh,
                       u16* __restrict__ Wm, u16* __restrict__ Wl,
                       u64* __restrict__ zp) {
  const int bid = blockIdx.x, tid = threadIdx.x;
  if (bid < 128) {
    int idx = (bid * 256 + tid) * 4;
    float4 v = *(const float4*)(W + idx);
    short h[4], m[4], l[4];
    split3(v.x, h[0], m[0], l[0]);
    split3(v.y, h[1], m[1], l[1]);
    split3(v.z, h[2], m[2], l[2]);
    split3(v.w, h[3], m[3], l[3]);
    *(ushort4*)(Wh + idx) = make_ushort4((u16)h[0], (u16)h[1], (u16)h[2], (u16)h[3]);
    *(ushort4*)(Wm + idx) = make_ushort4((u16)m[0], (u16)m[1], (u16)m[2], (u16)m[3]);
    *(ushort4*)(Wl + idx) = make_ushort4((u16)l[0], (u16)l[1], (u16)l[2], (u16)l[3]);
  } else {
    int i = (bid - 128) * 256 + tid;
    if (i < 26624) zp[i] = 0ull;
  }
}

// ---------------- K1: LDS MFMA GEMM, BM=128, split-K=8, 3 blk/CU ------------
// 1024 blocks. Per chunk per wave: 6 A-frag + 12 B-frag LDS reads feed 48
// MFMAs (R18: 15 reads / 24 MFMAs) -> 40% lower LDS pressure per FLOP and a
// deeper MFMA chain. Per-element accumulation order identical to R18/R19.
// LDS layout (u16 units): xh@0 xm@5120 xl@10240 (128x40 each),
//                         wh@15360 wm@17920 wl@20480 (64x40 each) = 46080 B.
__launch_bounds__(256, 3)
__global__ void k_gemm(const float* __restrict__ x, const u16* __restrict__ Whg,
                       const u16* __restrict__ Wmg, const u16* __restrict__ Wlg,
                       float* __restrict__ Lpart) {
  __shared__ __align__(16) u16 XS[23040];
  const int tid = threadIdx.x;
  const int bid = blockIdx.x;
  const int tile = bid >> 3, ks = bid & 7;
  const int row0 = tile * 128;
  const int k0 = ks * 256;
  const int lane = tid & 63, w = tid >> 6, l15 = lane & 15, l4 = lane >> 4;
  const int sr = tid >> 2, c8 = (tid & 3) * 8;

  f32x4 accA[2][4], accB[2][4];
#pragma unroll
  for (int g = 0; g < 2; g++)
#pragma unroll
    for (int eb = 0; eb < 4; eb++) { accA[g][eb] = (f32x4)0.f; accB[g][eb] = (f32x4)0.f; }

  float4 xq00, xq01, xq10, xq11;
  uint4 whv, wmv, wlv;
  const float* xp0 = x + (size_t)(row0 + sr) * DM + k0 + c8;        // rows 0..63
  const float* xp1 = xp0 + (size_t)64 * DM;                         // rows 64..127
  const u16* wph = Whg + (size_t)sr * DM + k0 + c8;                 // expert sr
  const u16* wpm = Wmg + (size_t)sr * DM + k0 + c8;
  const u16* wpl = Wlg + (size_t)sr * DM + k0 + c8;
  const int stA0 = sr * 40 + c8;
  const int stA1 = (64 + sr) * 40 + c8;
  const int stB = sr * 40 + c8;

#define LOADCH(KC) { \
    xq00 = *(const float4*)(xp0 + (KC)); \
    xq01 = *(const float4*)(xp0 + (KC) + 4); \
    xq10 = *(const float4*)(xp1 + (KC)); \
    xq11 = *(const float4*)(xp1 + (KC) + 4); \
    whv = *(const uint4*)(wph + (KC)); \
    wmv = *(const uint4*)(wpm + (KC)); \
    wlv = *(const uint4*)(wpl + (KC)); }

#define SPLIT8(Q0, Q1, DST) { \
    short ha[8], ma[8], la[8]; \
    split3(Q0.x, ha[0], ma[0], la[0]); \
    split3(Q0.y, ha[1], ma[1], la[1]); \
    split3(Q0.z, ha[2], ma[2], la[2]); \
    split3(Q0.w, ha[3], ma[3], la[3]); \
    split3(Q1.x, ha[4], ma[4], la[4]); \
    split3(Q1.y, ha[5], ma[5], la[5]); \
    split3(Q1.z, ha[6], ma[6], la[6]); \
    split3(Q1.w, ha[7], ma[7], la[7]); \
    bf16x8 xh8, xm8, xl8; \
    _Pragma("unroll") \
    for (int z = 0; z < 8; z++) { xh8[z] = ha[z]; xm8[z] = ma[z]; xl8[z] = la[z]; } \
    *(bf16x8*)(XS + 0     + (DST)) = xh8; \
    *(bf16x8*)(XS + 5120  + (DST)) = xm8; \
    *(bf16x8*)(XS + 10240 + (DST)) = xl8; }

#define WRITECH() { \
    SPLIT8(xq00, xq01, stA0); \
    SPLIT8(xq10, xq11, stA1); \
    *(uint4*)(XS + 15360 + stB) = whv; \
    *(uint4*)(XS + 17920 + stB) = wmv; \
    *(uint4*)(XS + 20480 + stB) = wlv; }

#define COMPUTECH() { \
    bf16x8 ah[2], am[2], al[2]; \
    _Pragma("unroll") \
    for (int g = 0; g < 2; g++) { \
      const int ar = (w * 32 + g * 16 + l15) * 40 + l4 * 8; \
      ah[g] = *(const bf16x8*)(XS + 0     + ar); \
      am[g] = *(const bf16x8*)(XS + 5120  + ar); \
      al[g] = *(const bf16x8*)(XS + 10240 + ar); \
    } \
    _Pragma("unroll") \
    for (int eb = 0; eb < 4; eb++) { \
      const int br = (eb * 16 + l15) * 40 + l4 * 8; \
      bf16x8 bh = *(const bf16x8*)(XS + 15360 + br); \
      bf16x8 bm = *(const bf16x8*)(XS + 17920 + br); \
      bf16x8 bl = *(const bf16x8*)(XS + 20480 + br); \
      _Pragma("unroll") \
      for (int g = 0; g < 2; g++) { \
        accA[g][eb] = __builtin_amdgcn_mfma_f32_16x16x32_bf16(ah[g], bh, accA[g][eb], 0, 0, 0); \
        accB[g][eb] = __builtin_amdgcn_mfma_f32_16x16x32_bf16(ah[g], bm, accB[g][eb], 0, 0, 0); \
        accB[g][eb] = __builtin_amdgcn_mfma_f32_16x16x32_bf16(am[g], bh, accB[g][eb], 0, 0, 0); \
        accB[g][eb] = __builtin_amdgcn_mfma_f32_16x16x32_bf16(am[g], bm, accB[g][eb], 0, 0, 0); \
        accB[g][eb] = __builtin_amdgcn_mfma_f32_16x16x32_bf16(ah[g], bl, accB[g][eb], 0, 0, 0); \
        accB[g][eb] = __builtin_amdgcn_mfma_f32_16x16x32_bf16(al[g], bh, accB[g][eb], 0, 0, 0); \
      } \
    } }

  LOADCH(0);
#pragma unroll 1
  for (int t = 0; t < 8; t++) {
    __syncthreads();          // previous chunk's compute done before overwrite
    WRITECH();
    __syncthreads();
    if (t < 7) LOADCH((t + 1) * 32);   // next-chunk loads hide under compute
    COMPUTECH();
  }

  // single f64 flush (per-element order identical to R18/R19)
  // C/D layout: col=lane&15 (expert), row=(lane>>4)*4+reg (token) [verified]
  float* outp = Lpart + (size_t)ks * NT * NE;
#pragma unroll
  for (int g = 0; g < 2; g++)
#pragma unroll
    for (int eb = 0; eb < 4; eb++)
#pragma unroll
      for (int r = 0; r < 4; r++) {
        int trow = w * 32 + g * 16 + l4 * 4 + r;
        outp[(size_t)(row0 + trow) * NE + eb * 16 + l15] =
            (float)((double)accA[g][eb][r] + (double)accB[g][eb][r]);
      }
}

// ---------------- K2: reduce 8 partials + center + softmax1 + gram ----------
__launch_bounds__(256)
__global__ void k_post(const float* __restrict__ Lpart, const float* __restrict__ b,
                       float* __restrict__ Lbuf, u64* __restrict__ CmAcc) {
  __shared__ float ms[64 * 68];
  const int tid = threadIdx.x, bid = blockIdx.x;
  const int tg = tid >> 2, q = tid & 3;
  const int row = bid * 64 + tg;
  float l[16], m[16];
  {
    double acc[16];
#pragma unroll
    for (int j = 0; j < 16; j++) acc[j] = 0.0;
#pragma unroll 1
    for (int ks = 0; ks < 8; ks++) {
      const float* p = Lpart + (size_t)ks * NT * NE + (size_t)row * NE + q * 16;
#pragma unroll
      for (int i = 0; i < 4; i++) {
        float4 v = *(const float4*)(p + i * 4);
        acc[i * 4 + 0] += (double)v.x; acc[i * 4 + 1] += (double)v.y;
        acc[i * 4 + 2] += (double)v.z; acc[i * 4 + 3] += (double)v.w;
      }
    }
#pragma unroll
    for (int i = 0; i < 4; i++) {
      float4 bv = *(const float4*)(b + q * 16 + i * 4);
      l[i * 4 + 0] = (float)acc[i * 4 + 0] + bv.x;
      l[i * 4 + 1] = (float)acc[i * 4 + 1] + bv.y;
      l[i * 4 + 2] = (float)acc[i * 4 + 2] + bv.z;
      l[i * 4 + 3] = (float)acc[i * 4 + 3] + bv.w;
    }
    float s = 0.f;
#pragma unroll
    for (int j = 0; j < 16; j++) s += l[j];
    s = warp4_sum(s);
    const float mean = s * (1.0f / 64.0f);
    float mx = -1e30f;
#pragma unroll
    for (int j = 0; j < 16; j++) { l[j] -= mean; mx = fmaxf(mx, l[j]); }
    mx = warp4_max(mx);
#pragma unroll
    for (int i = 0; i < 4; i++)
      *(float4*)(Lbuf + (size_t)row * NE + q * 16 + i * 4) =
          make_float4(l[i * 4], l[i * 4 + 1], l[i * 4 + 2], l[i * 4 + 3]);
    float ps = 0.f;
#pragma unroll
    for (int j = 0; j < 16; j++) { m[j] = expf(l[j] - mx); ps += m[j]; }
    ps = warp4_sum(ps);
    const float inv = 1.0f / ps;
#pragma unroll
    for (int j = 0; j < 16; j++) m[j] *= inv;
#pragma unroll
    for (int i = 0; i < 4; i++)
      *(float4*)(ms + tg * 68 + q * 16 + i * 4) =
          make_float4(m[i * 4], m[i * 4 + 1], m[i * 4 + 2], m[i * 4 + 3]);
  }
  __syncthreads();
  // gram partial -> slotted fx atomics (slot = bid & 3)
  const int gi0 = (tid >> 4) * 4;
  const int gj0 = (tid & 15) * 4;
  float ga[4][4];
#pragma unroll
  for (int a = 0; a < 4; a++)
#pragma unroll
    for (int c = 0; c < 4; c++) ga[a][c] = 0.f;
  for (int t = 0; t < 64; t++) {
    float4 a = *(const float4*)(ms + t * 68 + gi0);
    float4 bb = *(const float4*)(ms + t * 68 + gj0);
    ga[0][0] = fmaf(a.x, bb.x, ga[0][0]); ga[0][1] = fmaf(a.x, bb.y, ga[0][1]);
    ga[0][2] = fmaf(a.x, bb.z, ga[0][2]); ga[0][3] = fmaf(a.x, bb.w, ga[0][3]);
    ga[1][0] = fmaf(a.y, bb.x, ga[1][0]); ga[1][1] = fmaf(a.y, bb.y, ga[1][1]);
    ga[1][2] = fmaf(a.y, bb.z, ga[1][2]); ga[1][3] = fmaf(a.y, bb.w, ga[1][3]);
    ga[2][0] = fmaf(a.z, bb.x, ga[2][0]); ga[2][1] = fmaf(a.z, bb.y, ga[2][1]);
    ga[2][2] = fmaf(a.z, bb.z, ga[2][2]); ga[2][3] = fmaf(a.z, bb.w, ga[2][3]);
    ga[3][0] = fmaf(a.w, bb.x, ga[3][0]); ga[3][1] = fmaf(a.w, bb.y, ga[3][1]);
    ga[3][2] = fmaf(a.w, bb.z, ga[3][2]); ga[3][3] = fmaf(a.w, bb.w, ga[3][3]);
  }
  u64* slot = CmAcc + (size_t)(bid & 3) * 4096;
#pragma unroll
  for (int ii = 0; ii < 4; ii++)
#pragma unroll
    for (int jj = 0; jj < 4; jj++)
      atomicAdd(slot + (gi0 + ii) * 64 + gj0 + jj, to_fx(ga[ii][jj]));
}

// ---------------- K3: correction + softmax2 -> M0; emit P0 ------------------
__launch_bounds__(256)
__global__ void k_correct(const float* __restrict__ Lbuf, const u64* __restrict__ CmAcc,
                          float* __restrict__ M0, u64* __restrict__ p0Acc) {
  __shared__ float ms[64 * 68];
  __shared__ float Cs[4096];
  __shared__ float cred[256];
  const int tid = threadIdx.x, bid = blockIdx.x;
  const int tg = tid >> 2, q = tid & 3;
  const int lane = tid & 63, w = tid >> 6;
  const int row = bid * 64 + tg;
  float l[16], m[16];
#pragma unroll
  for (int i = 0; i < 4; i++) {
    float4 lv = *(const float4*)(Lbuf + (size_t)row * NE + q * 16 + i * 4);
    l[i * 4 + 0] = lv.x; l[i * 4 + 1] = lv.y; l[i * 4 + 2] = lv.z; l[i * 4 + 3] = lv.w;
  }
  {
    float mx = -1e30f;
#pragma unroll
    for (int j = 0; j < 16; j++) mx = fmaxf(mx, l[j]);
    mx = warp4_max(mx);
    float ps = 0.f;
#pragma unroll
    for (int j = 0; j < 16; j++) { m[j] = expf(l[j] - mx); ps += m[j]; }
    ps = warp4_sum(ps);
    const float inv = 1.0f / ps;
#pragma unroll
    for (int j = 0; j < 16; j++) m[j] *= inv;
#pragma unroll
    for (int i = 0; i < 4; i++)
      *(float4*)(ms + tg * 68 + q * 16 + i * 4) =
          make_float4(m[i * 4], m[i * 4 + 1], m[i * 4 + 2], m[i * 4 + 3]);
  }
#pragma unroll 4
  for (int i = 0; i < 16; i++) {
    int idx = tid + i * 256;
    u64 s = CmAcc[idx] + CmAcc[4096 + idx] + CmAcc[8192 + idx] + CmAcc[12288 + idx];
    float v = (float)((double)s * (1.0 / 4294967296.0));
    int r = idx >> 6, c = idx & 63;
    Cs[idx] = (r == c) ? 0.f : v;
  }
  __syncthreads();
  {
    float g[16];
#pragma unroll
    for (int j = 0; j < 16; j++) g[j] = 0.f;
    for (int f = 0; f < 64; f++) {
      float mf = ms[tg * 68 + f];
#pragma unroll
      for (int i = 0; i < 4; i++) {
        float4 cv = *(const float4*)(Cs + f * 64 + q * 16 + i * 4);
        g[i * 4 + 0] = fmaf(mf, cv.x, g[i * 4 + 0]);
        g[i * 4 + 1] = fmaf(mf, cv.y, g[i * 4 + 1]);
        g[i * 4 + 2] = fmaf(mf, cv.z, g[i * 4 + 2]);
        g[i * 4 + 3] = fmaf(mf, cv.w, g[i * 4 + 3]);
      }
    }
    float dot = 0.f;
#pragma unroll
    for (int j = 0; j < 16; j++) { g[j] *= 4.f; dot += m[j] * g[j]; }
    dot = warp4_sum(dot);
    float mx = -1e30f;
#pragma unroll
    for (int j = 0; j < 16; j++) {
      l[j] = l[j] - LTAX * (m[j] * (g[j] - dot));
      mx = fmaxf(mx, l[j]);
    }
    mx = warp4_max(mx);
    float ps = 0.f;
#pragma unroll
    for (int j = 0; j < 16; j++) { m[j] = expf(l[j] - mx); ps += m[j]; }
    ps = warp4_sum(ps);
    const float inv = 1.0f / ps;
#pragma unroll
    for (int j = 0; j < 16; j++) m[j] *= inv;
#pragma unroll
    for (int i = 0; i < 4; i++)
      *(float4*)(M0 + (size_t)row * NE + q * 16 + i * 4) =
          make_float4(m[i * 4], m[i * 4 + 1], m[i * 4 + 2], m[i * 4 + 3]);
  }
  {
    float cs[16];
#pragma unroll
    for (int j = 0; j < 16; j++) cs[j] = m[j];
#pragma unroll
    for (int j = 0; j < 16; j++) {
      cs[j] += __shfl_xor(cs[j], 4);  cs[j] += __shfl_xor(cs[j], 8);
      cs[j] += __shfl_xor(cs[j], 16); cs[j] += __shfl_xor(cs[j], 32);
    }
    if ((lane >> 2) == 0) {
#pragma unroll
      for (int j = 0; j < 16; j++) cred[w * 64 + lane * 16 + j] = cs[j];
    }
    __syncthreads();
    if (tid < 64)
      atomicAdd(p0Acc + (size_t)(bid & 15) * 64 + tid,
                to_fx(cred[tid] + cred[64 + tid] + cred[128 + tid] + cred[192 + tid]));
  }
}

// ---------------- K4: one factored Sinkhorn iteration -----------------------
__launch_bounds__(256)
__global__ void k_sink(const float* __restrict__ M0, const u64* __restrict__ pin,
                       u64* __restrict__ pout) {
  __shared__ u64 pred[4][64];
  __shared__ float fac[64];
  __shared__ float cred[256];
  const int tid = threadIdx.x, bid = blockIdx.x;
  const int tg = tid >> 2, q = tid & 3;
  const int lane = tid & 63, w = tid >> 6;
  const int row = bid * 64 + tg;
  {
    const int grp = tid >> 6, e = tid & 63;
    pred[grp][e] = pin[grp * 64 + e] + pin[(grp + 4) * 64 + e] +
                   pin[(grp + 8) * 64 + e] + pin[(grp + 12) * 64 + e];
  }
  __syncthreads();
  if (tid < 64) {
    u64 s = pred[0][tid] + pred[1][tid] + pred[2][tid] + pred[3][tid];
    float P = (float)((double)s * (1.0 / 4294967296.0));
    fac[tid] = 256.0f / fmaxf(P, 1e-30f);     // V(e)
  }
  __syncthreads();
  float mv[16];
#pragma unroll
  for (int i = 0; i < 4; i++) {
    float4 v = *(const float4*)(M0 + (size_t)row * NE + q * 16 + i * 4);
    mv[i * 4 + 0] = v.x; mv[i * 4 + 1] = v.y; mv[i * 4 + 2] = v.z; mv[i * 4 + 3] = v.w;
  }
  float Q = 0.f;
#pragma unroll
  for (int j = 0; j < 16; j++) Q = fmaf(mv[j], fac[q * 16 + j], Q);
  Q = warp4_sum(Q);
  const float U = 1.0f / fmaxf(Q, 1e-30f);
  float cs[16];
#pragma unroll
  for (int j = 0; j < 16; j++) cs[j] = U * mv[j];
#pragma unroll
  for (int j = 0; j < 16; j++) {
    cs[j] += __shfl_xor(cs[j], 4);  cs[j] += __shfl_xor(cs[j], 8);
    cs[j] += __shfl_xor(cs[j], 16); cs[j] += __shfl_xor(cs[j], 32);
  }
  if ((lane >> 2) == 0) {
#pragma unroll
    for (int j = 0; j < 16; j++) cred[w * 64 + lane * 16 + j] = cs[j];
  }
  __syncthreads();
  if (tid < 64)
    atomicAdd(pout + (size_t)(bid & 15) * 64 + tid,
              to_fx(cred[tid] + cred[64 + tid] + cred[128 + tid] + cred[192 + tid]));
}

// ---------------- K5: final M10 + damping + hysteresis + topk ---------------
__launch_bounds__(256)
__global__ void k_final(const float* __restrict__ M0, const u64* __restrict__ pin,
                        const float* __restrict__ pp, const void* __restrict__ pmask,
                        float* __restrict__ out) {
  __shared__ u64 pred[4][64];
  __shared__ float fac[64];
  __shared__ int s_cnt[256];
  __shared__ int s_flag;
  const int tid = threadIdx.x, bid = blockIdx.x;
  const int tg = tid >> 2, q = tid & 3;
  const int lane = tid & 63;
  const int row = bid * 64 + tg;

  {
    uint4 v = ((const uint4*)pmask)[tid];
    int c = 0; u32 ww;
    ww = v.x; c += ((ww & 0xffu) != 0) + ((ww & 0xff00u) != 0) + ((ww & 0xff0000u) != 0) + ((ww & 0xff000000u) != 0);
    ww = v.y; c += ((ww & 0xffu) != 0) + ((ww & 0xff00u) != 0) + ((ww & 0xff0000u) != 0) + ((ww & 0xff000000u) != 0);
    ww = v.z; c += ((ww & 0xffu) != 0) + ((ww & 0xff00u) != 0) + ((ww & 0xff0000u) != 0) + ((ww & 0xff000000u) != 0);
    ww = v.w; c += ((ww & 0xffu) != 0) + ((ww & 0xff00u) != 0) + ((ww & 0xff0000u) != 0) + ((ww & 0xff000000u) != 0);
    s_cnt[tid] = c;
    __syncthreads();
    for (int s = 128; s; s >>= 1) { if (tid < s) s_cnt[tid] += s_cnt[tid + s]; __syncthreads(); }
    if (tid == 0) { int n = s_cnt[0]; s_flag = (n > 384) ? 0 : ((n > 192) ? 2 : 1); }
  }
  {
    const int grp = tid >> 6, e = tid & 63;
    pred[grp][e] = pin[grp * 64 + e] + pin[(grp + 4) * 64 + e] +
                   pin[(grp + 8) * 64 + e] + pin[(grp + 12) * 64 + e];
  }
  __syncthreads();
  if (tid < 64) {
    u64 s = pred[0][tid] + pred[1][tid] + pred[2][tid] + pred[3][tid];
    float P = (float)((double)s * (1.0 / 4294967296.0));
    fac[tid] = 256.0f / fmaxf(P, 1e-30f);     // V10
  }
  __syncthreads();

  float mv[16];
#pragma unroll
  for (int i = 0; i < 4; i++) {
    float4 v = *(const float4*)(M0 + (size_t)row * NE + q * 16 + i * 4);
    mv[i * 4 + 0] = v.x; mv[i * 4 + 1] = v.y; mv[i * 4 + 2] = v.z; mv[i * 4 + 3] = v.w;
  }
  float Q = 0.f;
#pragma unroll
  for (int j = 0; j < 16; j++) Q = fmaf(mv[j], fac[q * 16 + j], Q);
  Q = warp4_sum(Q);
  const float U = 1.0f / fmaxf(Q, 1e-30f);
  float m[16];
#pragma unroll
  for (int j = 0; j < 16; j++) m[j] = U * mv[j] * fac[q * 16 + j];   // M10 row

  const int flag = s_flag;
  float pv[16], mk[16];
#pragma unroll
  for (int i = 0; i < 4; i++) {
    float4 v = *(const float4*)(pp + (size_t)row * NE + q * 16 + i * 4);
    pv[i * 4 + 0] = v.x; pv[i * 4 + 1] = v.y; pv[i * 4 + 2] = v.z; pv[i * 4 + 3] = v.w;
  }
  if (flag == 0) {
    const u32* pb = (const u32*)pmask + row * 16 + q * 4;
#pragma unroll
    for (int i = 0; i < 4; i++) {
      u32 ww = pb[i];
      mk[i * 4 + 0] = (ww & 0xffu) ? 1.f : 0.f;
      mk[i * 4 + 1] = (ww & 0xff00u) ? 1.f : 0.f;
      mk[i * 4 + 2] = (ww & 0xff0000u) ? 1.f : 0.f;
      mk[i * 4 + 3] = (ww & 0xff000000u) ? 1.f : 0.f;
    }
  } else if (flag == 1) {
    const int* pb = (const int*)pmask + (size_t)row * NE + q * 16;
#pragma unroll
    for (int j = 0; j < 16; j++) mk[j] = pb[j] ? 1.f : 0.f;
  } else {
    const float* pb = (const float*)pmask + (size_t)row * NE + q * 16;
#pragma unroll
    for (int j = 0; j < 16; j++) mk[j] = (pb[j] != 0.f) ? 1.f : 0.f;
  }
  float msum = 0.f;
#pragma unroll
  for (int j = 0; j < 16; j++) msum += mk[j];
  msum = warp4_sum(msum);
  const float hscale = HYST / fmaxf(msum, 1.0f);
  float v[16];
  float s = 0.f;
#pragma unroll
  for (int j = 0; j < 16; j++) {
    float base = (1.f - ALPHA) * pv[j] + ALPHA * m[j];
    v[j] = (1.f - HYST) * base + hscale * mk[j];
    s += v[j];
  }
  s = warp4_sum(s);
  const float inv = 1.0f / fmaxf(s, 1e-12f);
#pragma unroll
  for (int j = 0; j < 16; j++) v[j] *= inv;

  float* mout = out;
  float* kout = out + (size_t)NT * NE;
#pragma unroll
  for (int i = 0; i < 4; i++)
    *(float4*)(mout + (size_t)row * NE + q * 16 + i * 4) =
        make_float4(v[i * 4], v[i * 4 + 1], v[i * 4 + 2], v[i * 4 + 3]);

  int cnt[16];
#pragma unroll
  for (int j = 0; j < 16; j++) cnt[j] = 0;
  const int base = lane & ~3;
#pragma unroll
  for (int oq = 0; oq < 4; oq++) {
#pragma unroll
    for (int j2 = 0; j2 < 16; j2++) {
      float ov = __shfl(v[j2], base + oq, 64);
      int oe = oq * 16 + j2;
#pragma unroll
      for (int j = 0; j < 16; j++) {
        int me = q * 16 + j;
        if (ov > v[j] || (ov == v[j] && oe < me)) cnt[j]++;
      }
    }
  }
#pragma unroll
  for (int i = 0; i < 4; i++)
    *(float4*)(kout + (size_t)row * NE + q * 16 + i * 4) =
        make_float4(cnt[i * 4] < TOPK ? 1.f : 0.f, cnt[i * 4 + 1] < TOPK ? 1.f : 0.f,
                    cnt[i * 4 + 2] < TOPK ? 1.f : 0.f, cnt[i * 4 + 3] < TOPK ? 1.f : 0.f);
}

extern "C" void kernel_launch(void* const* d_in, const int* in_sizes, int n_in,
                              void* d_out, int out_size, void* d_ws, size_t ws_size,
                              hipStream_t stream) {
  const float* x = (const float*)d_in[0];
  const float* W = (const float*)d_in[1];
  const float* b = (const float*)d_in[2];
  const float* pp = (const float*)d_in[3];
  const void* pmask = d_in[4];
  float* out = (float*)d_out;

  unsigned char* wsb = (unsigned char*)d_ws;
  u16* Wh = (u16*)(wsb);                          // 256 KB
  u16* Wm = (u16*)(wsb + 262144);                 // 256 KB
  u16* Wl = (u16*)(wsb + 524288);                 // 256 KB
  float* Lpart = (float*)(wsb + 786432);          // 8 slices * 4 MB = 32 MB
  float* Lbuf = (float*)(wsb + 34340864);         // 4 MB
  float* M0buf = (float*)(wsb + 38535168);        // 4 MB
  u64* CmAcc = (u64*)(wsb + 42729472);            // 128 KB
  u64* pAcc = (u64*)(wsb + 42860544);             // 80 KB

  k_init<<<232, 256, 0, stream>>>(W, Wh, Wm, Wl, CmAcc);   // split W + zero acc
  k_gemm<<<1024, 256, 0, stream>>>(x, Wh, Wm, Wl, Lpart);
  k_post<<<256, 256, 0, stream>>>(Lpart, b, Lbuf, CmAcc);
  k_correct<<<256, 256, 0, stream>>>(Lbuf, CmAcc, M0buf, pAcc);
  for (int k = 1; k <= 9; k++)
    k_sink<<<256, 256, 0, stream>>>(M0buf, pAcc + (size_t)(k - 1) * 1024,
                                    pAcc + (size_t)k * 1024);
  k_final<<<256, 256, 0, stream>>>(M0buf, pAcc + (size_t)9 * 1024, pp, pmask, out);
}